// Round 3
// baseline (30643.915 us; speedup 1.0000x reference)
//
#include <hip/hip_runtime.h>
#include <math.h>

typedef unsigned int u32;
typedef unsigned long long u64;
typedef unsigned short u16;
typedef __attribute__((ext_vector_type(8))) short short8;
typedef __attribute__((ext_vector_type(4))) float f4;
typedef __attribute__((ext_vector_type(4))) u32 u32x4;

#define Ssz 2048
#define Bsz 64
#define Isz 256
#define Hsz 512
#define KC0 24   // 768/32 k-chunks, layer0 (256 x + 512 h)
#define KC1 32   // 1024/32 k-chunks, layer1 (512 y0 + 512 h1)
#define D0 5     // h0 ring depth (odd => parity-safe)
#define D1 3     // h1 ring depth (odd => parity-safe)

// ws layout (bytes). Weights PACKED u32 = bf16hi | bf16lo<<16, B-frag order.
#define WB0_OFF   0u
#define WB1_OFF   1572864u
#define BIAS0_OFF 3670016u
#define BIAS1_OFF 3672064u
#define FLAGS_OFF 3674112u   // per m: 64 u32; [nt]=L1 wave y0-read progress (32 used)
#define H0_OFF    3675136u   // [slot=5][m=4] x 32KB, chunk-major packed u32
#define H1_OFF    4330496u   // [slot=3][m=4] x 32KB
// end: 4723712

#define MFMA(a, b, c) __builtin_amdgcn_mfma_f32_16x16x32_bf16(a, b, c, 0, 0, 0)

__device__ __forceinline__ u16 f2bf(float f) {
  union { float f; u32 u; } v; v.f = f;
  u32 r = v.u + 0x7FFFu + ((v.u >> 16) & 1u);
  return (u16)(r >> 16);
}
__device__ __forceinline__ float bf2f(u16 h) {
  union { u32 u; float f; } v; v.u = ((u32)h) << 16;
  return v.f;
}
__device__ __forceinline__ u32 packbf(float f) {
  u16 hi = f2bf(f);
  u16 lo = f2bf(f - bf2f(hi));
  return (u32)hi | ((u32)lo << 16);
}
__device__ __forceinline__ void unpack2(u32 w0, u32 w1, u32& hi, u32& lo) {
  hi = __builtin_amdgcn_perm(w1, w0, 0x05040100u);
  lo = __builtin_amdgcn_perm(w1, w0, 0x07060302u);
}
__device__ __forceinline__ void cvt2(float a, float b, u32& hi, u32& lo) {
  u16 ha = f2bf(a), hb = f2bf(b);
  u16 la = f2bf(a - bf2f(ha)), lb = f2bf(b - bf2f(hb));
  hi = (u32)ha | ((u32)hb << 16);
  lo = (u32)la | ((u32)lb << 16);
}
__device__ __forceinline__ float ftanh(float xx) {
  float x = fminf(20.f, fmaxf(-20.f, xx));
  float e = __expf(2.f * x);
  return (e - 1.f) / (e + 1.f);
}

union frag { short8 s; u32 w[4]; };

// LLC-coherent (agent-scope) accessors
__device__ __forceinline__ u64 ald64(const u64* p) {
  return __hip_atomic_load(p, __ATOMIC_RELAXED, __HIP_MEMORY_SCOPE_AGENT);
}
__device__ __forceinline__ u32 ald32(const u32* p) {
  return __hip_atomic_load(p, __ATOMIC_RELAXED, __HIP_MEMORY_SCOPE_AGENT);
}
__device__ __forceinline__ void ast32(u32* p, u32 v) {
  __hip_atomic_store(p, v, __ATOMIC_RELAXED, __HIP_MEMORY_SCOPE_AGENT);
}

// Self-validating spin-load of 8 chunks (16KB/wave half). Each stored u32
// carries a 1-bit step tag at bit16 (LSB of lo-bf16). Accept when ALL words
// carry the expected parity. Per-word tags make word-tearing safe.
__device__ __forceinline__ void spin8(const u32* rb, int cbase, int lane,
                                      u32 par, u64 (&hb)[8][4]) {
  const u64 M = 0x0001000000010000ull;
  const u64 E = par ? M : 0ull;
  const u64* base = (const u64*)(rb + cbase * 512 + lane * 8);
  while (1) {
    #pragma unroll
    for (int i = 0; i < 8; ++i) {
      #pragma unroll
      for (int v = 0; v < 4; ++v) hb[i][v] = ald64(base + i * 256 + v);
    }
    int ok = 1;
    #pragma unroll
    for (int i = 0; i < 8; ++i)
      #pragma unroll
      for (int v = 0; v < 4; ++v) ok &= (int)((hb[i][v] & M) == E);
    if (__all(ok)) break;
  }
}

// unpack one chunk's 8 packed u32 (hi/lo bf16) and feed 3 MFMAs into
// rotating accumulator chains (4 independent chains hide dep-latency at
// 1 wave/SIMD).
#define HSTEP(ii, WH, WL) do { frag h_, l_;                                 \
    unpack2((u32)hb[ii][0], (u32)(hb[ii][0] >> 32), h_.w[0], l_.w[0]);      \
    unpack2((u32)hb[ii][1], (u32)(hb[ii][1] >> 32), h_.w[1], l_.w[1]);      \
    unpack2((u32)hb[ii][2], (u32)(hb[ii][2] >> 32), h_.w[2], l_.w[2]);      \
    unpack2((u32)hb[ii][3], (u32)(hb[ii][3] >> 32), h_.w[3], l_.w[3]);      \
    c[(ii) & 3]       = MFMA(h_.s, WH, c[(ii) & 3]);                        \
    c[((ii) + 1) & 3] = MFMA(h_.s, WL, c[((ii) + 1) & 3]);                  \
    c[((ii) + 2) & 3] = MFMA(l_.s, WH, c[((ii) + 2) & 3]);                  \
  } while (0)

__global__ void prep_weights(const float* __restrict__ Wih0, const float* __restrict__ Whh0,
                             const float* __restrict__ bih0, const float* __restrict__ bhh0,
                             const float* __restrict__ Wih1, const float* __restrict__ Whh1,
                             const float* __restrict__ bih1, const float* __restrict__ bhh1,
                             const int* __restrict__ mih0, const int* __restrict__ mhh0,
                             const int* __restrict__ mih1, const int* __restrict__ mhh1,
                             char* __restrict__ ws) {
  const int L0E = 768 * 512, L1E = 1024 * 512;
  const int TAGN = 131072;   // H0 slots 0,2,4 (98304) + H1 slot 2 (32768)
  int e = blockIdx.x * blockDim.x + threadIdx.x;
  if (e >= L0E + L1E + 1024 + TAGN) return;
  if (e < L0E) {
    int f = e >> 9, fe = e & 511;
    int lane = fe >> 3, j = fe & 7;
    int n = lane & 15, q = lane >> 4;
    int nt = f / KC0, kc = f % KC0;
    int u = nt * 16 + n, k = kc * 32 + q * 8 + j;
    float w;
    if (k < 256) w = Wih0[u * 256 + k] * (float)mih0[u * 256 + k];
    else         w = Whh0[u * 512 + (k - 256)] * (float)mhh0[u * 512 + (k - 256)];
    ((u32*)(ws + WB0_OFF))[e] = packbf(w);
  } else if (e < L0E + L1E) {
    int e1 = e - L0E;
    int f = e1 >> 9, fe = e1 & 511;
    int lane = fe >> 3, j = fe & 7;
    int n = lane & 15, q = lane >> 4;
    int nt = f >> 5, kc = f & 31;
    int u = nt * 16 + n, k = kc * 32 + q * 8 + j;
    float w;
    if (k < 512) w = Wih1[u * 512 + k] * (float)mih1[u * 512 + k];
    else         w = Whh1[u * 512 + (k - 512)] * (float)mhh1[u * 512 + (k - 512)];
    ((u32*)(ws + WB1_OFF))[e1] = packbf(w);
  } else if (e < L0E + L1E + 1024) {
    int b2 = e - L0E - L1E;
    if (b2 < 512) ((float*)(ws + BIAS0_OFF))[b2] = bih0[b2] + bhh0[b2];
    else          ((float*)(ws + BIAS1_OFF))[b2 - 512] = bih1[b2 - 512] + bhh1[b2 - 512];
  } else {
    // tag-init 0x00010000: value ~0, tag=1. H0 slot s first written at t=s
    // with tag s&1 and first read expecting s&1 — even slots must init to
    // parity 1 to reject stale reads; slot 4's init doubles as valid
    // h0[-1]=0 (parity 1). H1: slot 2 init parity 1; slot 0 stays zero =
    // valid h1[0]=0 (parity 0); slot 1 zero (first read expects parity 1).
    int ti = e - (L0E + L1E + 1024);
    u32* dst;
    if (ti < 98304) {                       // H0 slots 0,2,4
      int s = ti >> 15;
      dst = (u32*)(ws + H0_OFF) + (2 * s) * 32768 + (ti & 32767);
    } else {                                // H1 slot 2
      dst = (u32*)(ws + H1_OFF) + 2 * 32768 + (ti - 98304);
    }
    *dst = 0x00010000u;
  }
}

// H chunk-major layout per (slot,m) 32KB: elem (b local 0..15, u 0..511) at
// u32 index  c*512 + (b + 16*((u&31)>>3))*8 + (u&7),  c = u>>5.
// A consumer wave's chunk read = 64 lanes x 32B fully contiguous (2KB).

// One free-running wave computes h0[t][m*16..+16][nt*16..+16] with FULL K.
// No __syncthreads, no LDS. Serial chain/step: detect -> 48 MFMA -> tanh ->
// 4 stores.
__device__ __forceinline__ void run0(const float* __restrict__ x, char* __restrict__ ws,
                                     int m, int nt, int lane) {
  const int n = lane & 15, q = lane >> 4;
  const int b0 = m * 16;
  const u32* WB = (const u32*)(ws + WB0_OFF);
  const float bs = ((const float*)(ws + BIAS0_OFF))[nt * 16 + n];
  const u32* fl = (const u32*)(ws + FLAGS_OFF) + m * 64;

  short8 Whi[KC0], Wlo[KC0];   // 192 VGPR
  #pragma unroll
  for (int kc = 0; kc < KC0; ++kc) {
    const u32* pw = WB + ((nt * KC0 + kc) * 64 + lane) * 8;
    u32x4 a = *(const u32x4*)pw;
    u32x4 b = *(const u32x4*)(pw + 4);
    frag h, l;
    unpack2(a.x, a.y, h.w[0], l.w[0]);
    unpack2(a.z, a.w, h.w[1], l.w[1]);
    unpack2(b.x, b.y, h.w[2], l.w[2]);
    unpack2(b.z, b.w, h.w[3], l.w[3]);
    Whi[kc] = h.s; Wlo[kc] = l.s;
  }

  f4 xp[8][2];
  auto loadx = [&](int t) {
    #pragma unroll
    for (int i = 0; i < 8; ++i) {
      const float* sx = x + ((long)t * Bsz + b0 + n) * Isz + i * 32 + q * 8;
      xp[i][0] = *(const f4*)sx;
      xp[i][1] = *(const f4*)(sx + 4);
    }
  };
  short8 Axh[8], Axl[8];
  auto cvtx = [&]() {
    #pragma unroll
    for (int i = 0; i < 8; ++i) {
      frag h, l;
      cvt2(xp[i][0].x, xp[i][0].y, h.w[0], l.w[0]);
      cvt2(xp[i][0].z, xp[i][0].w, h.w[1], l.w[1]);
      cvt2(xp[i][1].x, xp[i][1].y, h.w[2], l.w[2]);
      cvt2(xp[i][1].z, xp[i][1].w, h.w[3], l.w[3]);
      Axh[i] = h.s; Axl[i] = l.s;
    }
  };
  loadx(0); cvtx();

  const int sbase = (nt >> 1) * 512 +
                    (q * 4 + 16 * (((nt & 1) << 1) + (n >> 3))) * 8 + (n & 7);
  int sR = D0 - 1, sW = 0, last1 = 0;
  u64 hb[8][4];

  for (int t = 0; t < Ssz; ++t) {
    f4 c[4] = {{0,0,0,0},{0,0,0,0},{0,0,0,0},{0,0,0,0}};
    // x-part (independent of h) — off critical path
    #pragma unroll
    for (int i = 0; i < 8; ++i) {
      c[i & 3]       = MFMA(Axh[i], Whi[i], c[i & 3]);
      c[(i + 1) & 3] = MFMA(Axh[i], Wlo[i], c[(i + 1) & 3]);
      c[(i + 2) & 3] = MFMA(Axl[i], Whi[i], c[(i + 2) & 3]);
    }
    loadx(t + 1 < Ssz ? t + 1 : t);       // issue next-x; lands during spin
    const u32 pr = (u32)((t - 1) & 1);    // h0[t-1] tag
    const u32* rb = (const u32*)(ws + H0_OFF) + (sR * 4 + m) * 8192;
    spin8(rb, 0, lane, pr, hb);
    #pragma unroll
    for (int i = 0; i < 8; ++i) HSTEP(i, Whi[8 + i], Wlo[8 + i]);
    spin8(rb, 8, lane, pr, hb);
    #pragma unroll
    for (int i = 0; i < 8; ++i) HSTEP(i, Whi[16 + i], Wlo[16 + i]);
    f4 s = (c[0] + c[1]) + (c[2] + c[3]);
    // L1 backpressure before overwriting slot holding h0[t-5]: all 32 L1
    // waves of m must have accepted y0[t-5] (flag >= t-4). Snapshot-cached.
    if (last1 < t - 4) {
      while (1) {
        int mn = 1 << 30;
        #pragma unroll
        for (int i = 0; i < 32; ++i) { int f = (int)ald32(fl + i); mn = f < mn ? f : mn; }
        if (mn >= t - 4) { last1 = mn; break; }
      }
    }
    u32* wb = (u32*)(ws + H0_OFF) + (sW * 4 + m) * 8192;
    const u32 tb = (u32)(t & 1) << 16;
    #pragma unroll
    for (int r = 0; r < 4; ++r) {
      float val = ftanh(bs + s[r]);
      ast32(wb + sbase + r * 8, (packbf(val) & 0xFFFEFFFFu) | tb);
    }
    sR = (sR == D0 - 1) ? 0 : sR + 1;
    sW = (sW == D0 - 1) ? 0 : sW + 1;
    cvtx();                               // loads long landed
  }
}

__device__ __forceinline__ void run1(char* __restrict__ ws, float* __restrict__ out,
                                     int m, int nt, int lane) {
  const int n = lane & 15, q = lane >> 4;
  const u32* WB = (const u32*)(ws + WB1_OFF);
  const float bs = ((const float*)(ws + BIAS1_OFF))[nt * 16 + n];
  u32* myflag = (u32*)(ws + FLAGS_OFF) + m * 64 + nt;

  short8 Whi[KC1], Wlo[KC1];   // 256 VGPR
  #pragma unroll
  for (int kc = 0; kc < KC1; ++kc) {
    const u32* pw = WB + ((nt * KC1 + kc) * 64 + lane) * 8;
    u32x4 a = *(const u32x4*)pw;
    u32x4 b = *(const u32x4*)(pw + 4);
    frag h, l;
    unpack2(a.x, a.y, h.w[0], l.w[0]);
    unpack2(a.z, a.w, h.w[1], l.w[1]);
    unpack2(b.x, b.y, h.w[2], l.w[2]);
    unpack2(b.z, b.w, h.w[3], l.w[3]);
    Whi[kc] = h.s; Wlo[kc] = l.s;
  }

  const int sbase = (nt >> 1) * 512 +
                    (q * 4 + 16 * (((nt & 1) << 1) + (n >> 3))) * 8 + (n & 7);
  int sR0 = 0, sR1 = 0, sW1 = 1;
  u64 hb[8][4];

  for (int t = 1; t <= Ssz; ++t) {
    f4 c[4] = {{0,0,0,0},{0,0,0,0},{0,0,0,0},{0,0,0,0}};
    const u32 pr = (u32)((t - 1) & 1);
    // y0[t-1] FIRST (L0 runs ahead -> usually ready); publish read-done after.
    const u32* rb0 = (const u32*)(ws + H0_OFF) + (sR0 * 4 + m) * 8192;
    spin8(rb0, 0, lane, pr, hb);
    #pragma unroll
    for (int i = 0; i < 8; ++i) HSTEP(i, Whi[i], Wlo[i]);
    spin8(rb0, 8, lane, pr, hb);
    #pragma unroll
    for (int i = 0; i < 8; ++i) HSTEP(i, Whi[8 + i], Wlo[8 + i]);
    if (lane == 0) ast32(myflag, (u32)t);
    // h1[t-1]: tight self-recurrence (mutual detect bounds peer lag to 1)
    const u32* rb1 = (const u32*)(ws + H1_OFF) + (sR1 * 4 + m) * 8192;
    spin8(rb1, 0, lane, pr, hb);
    #pragma unroll
    for (int i = 0; i < 8; ++i) HSTEP(i, Whi[16 + i], Wlo[16 + i]);
    spin8(rb1, 8, lane, pr, hb);
    #pragma unroll
    for (int i = 0; i < 8; ++i) HSTEP(i, Whi[24 + i], Wlo[24 + i]);
    f4 s = (c[0] + c[1]) + (c[2] + c[3]);
    u32* wb = (u32*)(ws + H1_OFF) + (sW1 * 4 + m) * 8192;
    const u32 tb = (u32)(t & 1) << 16;
    #pragma unroll
    for (int r = 0; r < 4; ++r) {
      float val = ftanh(bs + s[r]);
      ast32(wb + sbase + r * 8, (packbf(val) & 0xFFFEFFFFu) | tb);
      if (t == Ssz) out[(m * 16 + q * 4 + r) * Hsz + nt * 16 + n] = val;
    }
    sR0 = (sR0 == D0 - 1) ? 0 : sR0 + 1;
    sR1 = (sR1 == D1 - 1) ? 0 : sR1 + 1;
    sW1 = (sW1 == D1 - 1) ? 0 : sW1 + 1;
  }
}

__global__ __launch_bounds__(256, 1) void rnn_persist(const float* __restrict__ x,
                                                      char* __restrict__ ws,
                                                      float* __restrict__ out) {
  const int tid = threadIdx.x;
  const int w = tid >> 6, lane = tid & 63;
  const int wg = blockIdx.x;
  if (wg < 32) {
    // m in 0..3, nt in 0..31 (8 WGs x 4 waves per m)
    run0(x, ws, wg >> 3, (wg & 7) * 4 + w, lane);
  } else {
    const int g = wg - 32;
    run1(ws, out, g >> 3, (g & 7) * 4 + w, lane);
  }
}

extern "C" void kernel_launch(void* const* d_in, const int* in_sizes, int n_in,
                              void* d_out, int out_size, void* d_ws, size_t ws_size,
                              hipStream_t stream) {
  const float* x    = (const float*)d_in[0];
  const float* Wih0 = (const float*)d_in[1];
  const float* Whh0 = (const float*)d_in[2];
  const float* bih0 = (const float*)d_in[3];
  const float* bhh0 = (const float*)d_in[4];
  const float* Wih1 = (const float*)d_in[5];
  const float* Whh1 = (const float*)d_in[6];
  const float* bih1 = (const float*)d_in[7];
  const float* bhh1 = (const float*)d_in[8];
  const int* mih0   = (const int*)d_in[9];
  const int* mhh0   = (const int*)d_in[10];
  const int* mih1   = (const int*)d_in[11];
  const int* mhh1   = (const int*)d_in[12];
  char* ws = (char*)d_ws;

  // zero flags + H0(5 slots) + H1(3 slots); prep then writes tag-init slots
  hipMemsetAsync(ws + FLAGS_OFF, 0, 1024 + 655360 + 393216, stream);

  const int tot = 768 * 512 + 1024 * 512 + 1024 + 131072;
  prep_weights<<<(tot + 255) / 256, 256, 0, stream>>>(
      Wih0, Whh0, bih0, bhh0, Wih1, Whh1, bih1, bhh1,
      mih0, mhh0, mih1, mhh1, ws);

  rnn_persist<<<64, 256, 0, stream>>>(x, ws, (float*)d_out);
}